// Round 1
// baseline (348.372 us; speedup 1.0000x reference)
//
#include <hip/hip_runtime.h>

#define L 4096
#define HH 64
#define WW 64
#define DM 96
#define DI 192
#define DSTATE 16
#define DTR 6
#define NC 38   // DTR + 2*DSTATE
#define KD 4
#define CHUNK 32
#define NCHUNK 128  // L / CHUNK

__device__ __forceinline__ float silu_f(float v){ return v / (1.f + __expf(-v)); }
__device__ __forceinline__ float softplus_f(float v){ return fmaxf(v, 0.f) + log1pf(__expf(-fabsf(v))); }
// scan index l -> row-major spatial index for direction k
__device__ __forceinline__ int spat(int k, int l){
  int ll = (k & 2) ? (L - 1 - l) : l;
  return (k & 1) ? (((ll & 63) << 6) | (ll >> 6)) : ll;
}

// ---------------- Kernel 1: in_proj -> x_ (L x 192), silu(z) (L x 192) ----------------
__global__ void k_inproj(const float* __restrict__ x, const float* __restrict__ w,
                         float* __restrict__ xo, float* __restrict__ sz){
  int l = blockIdx.x, t = threadIdx.x;   // block = 384 threads, one per output channel
  __shared__ float xl[DM];
  if (t < DM) xl[t] = x[l*DM + t];
  __syncthreads();
  const float* wr = w + t*DM;
  float acc = 0.f;
  #pragma unroll
  for (int c = 0; c < DM; c++) acc += xl[c] * wr[c];
  if (t < DI) xo[l*DI + t] = acc;
  else        sz[l*DI + (t - DI)] = silu_f(acc);
}

// ---------------- Kernel 2: depthwise 3x3 conv + bias + silu -> xc ----------------
__global__ void k_conv(const float* __restrict__ xi, const float* __restrict__ cw,
                       const float* __restrict__ cb, float* __restrict__ xc){
  int idx = blockIdx.x * blockDim.x + threadIdx.x;
  if (idx >= L*DI) return;
  int d = idx % DI, l = idx / DI;
  int h = l >> 6, w = l & 63;
  float acc = cb[d];
  #pragma unroll
  for (int dy = 0; dy < 3; dy++){
    int hh = h + dy - 1;
    if (hh < 0 || hh >= HH) continue;
    #pragma unroll
    for (int dx = 0; dx < 3; dx++){
      int ww = w + dx - 1;
      if (ww < 0 || ww >= WW) continue;
      acc += xi[(hh*WW + ww)*DI + d] * cw[(dy*3 + dx)*DI + d];
    }
  }
  xc[idx] = silu_f(acc);
}

// ---------------- Kernel 3: x_dbl[k][l][38] = x_proj_w[k] @ xs[k,:,l] ----------------
__global__ void k_xdbl(const float* __restrict__ xc, const float* __restrict__ pw,
                       float* __restrict__ xdbl){
  int k    = blockIdx.x >> 9;    // grid = 4*512
  int tile = blockIdx.x & 511;
  int l0   = tile * 8;
  int t    = threadIdx.x;        // 320 threads
  __shared__ float xt[8*DI];
  for (int j = t; j < 8*DI; j += 320){
    int row = j / DI, d = j - row*DI;
    xt[j] = xc[spat(k, l0 + row)*DI + d];
  }
  __syncthreads();
  int row = t / 40, c = t % 40;
  if (c < NC){
    const float* pr = pw + (k*NC + c)*DI;
    const float* xr = xt + row*DI;
    float acc = 0.f;
    #pragma unroll 8
    for (int d = 0; d < DI; d++) acc += xr[d] * pr[d];
    xdbl[(k*L + l0 + row)*NC + c] = acc;
  }
}

// ---------------- Kernel 4: scan pass 1 — per-chunk aggregates (P, G) ----------------
__global__ void k_scan1(const float* __restrict__ xdbl, const float* __restrict__ xc,
                        const float* __restrict__ dtw, const float* __restrict__ dtb,
                        const float* __restrict__ alogs,
                        float* __restrict__ Pb, float* __restrict__ Gb){
  int k  = blockIdx.x >> 7;   // grid = 4*128
  int ch = blockIdx.x & 127;
  int l0 = ch * CHUNK;
  int d  = threadIdx.x;       // 192 threads
  __shared__ float xd[CHUNK*NC];
  for (int j = d; j < CHUNK*NC; j += DI) xd[j] = xdbl[(k*L + l0)*NC + j];
  float wr[DTR];
  #pragma unroll
  for (int r = 0; r < DTR; r++) wr[r] = dtw[(k*DI + d)*DTR + r];
  float bb = dtb[k*DI + d];
  float A[DSTATE];
  #pragma unroll
  for (int n = 0; n < DSTATE; n++) A[n] = -__expf(alogs[(k*DI + d)*DSTATE + n]);
  float P[DSTATE], G[DSTATE];
  #pragma unroll
  for (int n = 0; n < DSTATE; n++){ P[n] = 1.f; G[n] = 0.f; }
  __syncthreads();
  for (int i = 0; i < CHUNK; i++){
    int l = l0 + i;
    float xval = xc[spat(k, l)*DI + d];
    const float* row = xd + i*NC;
    float dv = bb;
    #pragma unroll
    for (int r = 0; r < DTR; r++) dv += wr[r] * row[r];
    dv = softplus_f(dv);
    float tv = dv * xval;
    #pragma unroll
    for (int n = 0; n < DSTATE; n++){
      float dA = __expf(dv * A[n]);
      G[n] = dA * G[n] + tv * row[DTR + n];
      P[n] *= dA;
    }
  }
  float* Pp = Pb + ((k*NCHUNK + ch)*DI + d)*DSTATE;
  float* Gp = Gb + ((k*NCHUNK + ch)*DI + d)*DSTATE;
  #pragma unroll
  for (int n = 0; n < DSTATE; n++){ Pp[n] = P[n]; Gp[n] = G[n]; }
}

// ---------------- Kernel 5: scan pass 2 — prefix over chunks ----------------
__global__ void k_scan2(const float* __restrict__ Pb, const float* __restrict__ Gb,
                        float* __restrict__ Hin){
  int k  = blockIdx.y;
  int dn = blockIdx.x * blockDim.x + threadIdx.x;  // < 3072 = DI*DSTATE
  float h = 0.f;
  for (int c = 0; c < NCHUNK; c++){
    int idx = (k*NCHUNK + c)*DI*DSTATE + dn;
    Hin[idx] = h;
    h = Pb[idx]*h + Gb[idx];
  }
}

// ---------------- Kernel 6: scan pass 3 — replay chunks, emit out_y ----------------
__global__ void k_scan3(const float* __restrict__ xdbl, const float* __restrict__ xc,
                        const float* __restrict__ dtw, const float* __restrict__ dtb,
                        const float* __restrict__ alogs, const float* __restrict__ Dsv,
                        const float* __restrict__ Hin, float* __restrict__ outy){
  int k  = blockIdx.x >> 7;
  int ch = blockIdx.x & 127;
  int l0 = ch * CHUNK;
  int d  = threadIdx.x;
  __shared__ float xd[CHUNK*NC];
  for (int j = d; j < CHUNK*NC; j += DI) xd[j] = xdbl[(k*L + l0)*NC + j];
  float wr[DTR];
  #pragma unroll
  for (int r = 0; r < DTR; r++) wr[r] = dtw[(k*DI + d)*DTR + r];
  float bb = dtb[k*DI + d];
  float A[DSTATE];
  #pragma unroll
  for (int n = 0; n < DSTATE; n++) A[n] = -__expf(alogs[(k*DI + d)*DSTATE + n]);
  float h[DSTATE];
  #pragma unroll
  for (int n = 0; n < DSTATE; n++) h[n] = Hin[(k*NCHUNK + ch)*DI*DSTATE + d*DSTATE + n];
  float Dv = Dsv[k*DI + d];
  __syncthreads();
  for (int i = 0; i < CHUNK; i++){
    int l = l0 + i;
    float xval = xc[spat(k, l)*DI + d];
    const float* row = xd + i*NC;
    float dv = bb;
    #pragma unroll
    for (int r = 0; r < DTR; r++) dv += wr[r] * row[r];
    dv = softplus_f(dv);
    float tv = dv * xval;
    float y = Dv * xval;
    #pragma unroll
    for (int n = 0; n < DSTATE; n++){
      float dA = __expf(dv * A[n]);
      h[n] = dA * h[n] + tv * row[DTR + n];
      y += h[n] * row[DTR + DSTATE + n];
    }
    outy[(k*L + l)*DI + d] = y;
  }
}

// ---------------- Kernel 7: sum over k + LayerNorm + *silu(z) + out proj ----------------
__global__ void k_final(const float* __restrict__ outy, const float* __restrict__ sz,
                        const float* __restrict__ g, const float* __restrict__ b,
                        const float* __restrict__ ow, float* __restrict__ out){
  int l = blockIdx.x, t = threadIdx.x;  // 192 threads
  __shared__ float ym[DI];
  __shared__ float red[6];
  float y = 0.f;
  #pragma unroll
  for (int k = 0; k < KD; k++) y += outy[(k*L + l)*DI + t];
  float s = y, s2 = y*y;
  #pragma unroll
  for (int off = 32; off; off >>= 1){ s += __shfl_down(s, off); s2 += __shfl_down(s2, off); }
  int wave = t >> 6, lane = t & 63;
  if (lane == 0){ red[wave] = s; red[3 + wave] = s2; }
  __syncthreads();
  float S  = red[0] + red[1] + red[2];
  float SQ = red[3] + red[4] + red[5];
  float mu  = S * (1.f/DI);
  float var = SQ * (1.f/DI) - mu*mu;
  float yn = (y - mu) * rsqrtf(var + 1e-5f) * g[t] + b[t];
  ym[t] = yn * sz[l*DI + t];
  __syncthreads();
  if (t < DM){
    const float* wr = ow + t*DI;
    float acc = 0.f;
    #pragma unroll 8
    for (int d = 0; d < DI; d++) acc += ym[d] * wr[d];
    out[l*DM + t] = acc;
  }
}

extern "C" void kernel_launch(void* const* d_in, const int* in_sizes, int n_in,
                              void* d_out, int out_size, void* d_ws, size_t ws_size,
                              hipStream_t stream){
  const float* x   = (const float*)d_in[0];
  const float* ipw = (const float*)d_in[1];
  const float* cw  = (const float*)d_in[2];
  const float* cb  = (const float*)d_in[3];
  const float* pw  = (const float*)d_in[4];
  const float* dtw = (const float*)d_in[5];
  const float* dtb = (const float*)d_in[6];
  const float* alg = (const float*)d_in[7];
  const float* Dsv = (const float*)d_in[8];
  const float* lng = (const float*)d_in[9];
  const float* lnb = (const float*)d_in[10];
  const float* ow  = (const float*)d_in[11];
  float* out = (float*)d_out;

  float* ws   = (float*)d_ws;
  float* x_   = ws; ws += L*DI;
  float* sz   = ws; ws += L*DI;
  float* xc   = ws; ws += L*DI;
  float* xdbl = ws; ws += KD*L*NC;
  float* Pb   = ws; ws += KD*NCHUNK*DI*DSTATE;
  float* Gb   = ws; ws += KD*NCHUNK*DI*DSTATE;
  float* Hin  = ws; ws += KD*NCHUNK*DI*DSTATE;
  float* oy   = ws; ws += KD*L*DI;

  k_inproj<<<L, 384, 0, stream>>>(x, ipw, x_, sz);
  k_conv<<<(L*DI + 255)/256, 256, 0, stream>>>(x_, cw, cb, xc);
  k_xdbl<<<KD*512, 320, 0, stream>>>(xc, pw, xdbl);
  k_scan1<<<KD*NCHUNK, DI, 0, stream>>>(xdbl, xc, dtw, dtb, alg, Pb, Gb);
  k_scan2<<<dim3(12, KD), 256, 0, stream>>>(Pb, Gb, Hin);
  k_scan3<<<KD*NCHUNK, DI, 0, stream>>>(xdbl, xc, dtw, dtb, alg, Dsv, Hin, oy);
  k_final<<<L, DI, 0, stream>>>(oy, sz, lng, lnb, ow, out);
}

// Round 2
// 232.475 us; speedup vs baseline: 1.4985x; 1.4985x over previous
//
#include <hip/hip_runtime.h>

#define L 4096
#define HH 64
#define WW 64
#define DM 96
#define DI 192
#define DSTATE 16
#define DTR 6
#define NC 38   // DTR + 2*DSTATE
#define KD 4
#define CHUNK 32
#define NCHUNK 128  // L / CHUNK
#define TL 8     // l-tile for in_proj

__device__ __forceinline__ float silu_f(float v){ return v / (1.f + __expf(-v)); }
__device__ __forceinline__ float softplus_f(float v){ return fmaxf(v, 0.f) + log1pf(__expf(-fabsf(v))); }
// scan index l -> row-major spatial index for direction k
__device__ __forceinline__ int spat(int k, int l){
  int ll = (k & 2) ? (L - 1 - l) : l;
  return (k & 1) ? (((ll & 63) << 6) | (ll >> 6)) : ll;
}

// ---------------- Kernel 0: weight transposes (coalesced-access layouts) ----------------
__global__ void k_prep(const float* __restrict__ ipw, const float* __restrict__ pw,
                       const float* __restrict__ ow,
                       float* __restrict__ ipwT, float* __restrict__ pwT,
                       float* __restrict__ owT){
  int i = blockIdx.x * 256 + threadIdx.x;
  if (i < 384*DM){ int o = i / DM, c = i % DM; ipwT[c*384 + o] = ipw[i]; }
  int j = i - 384*DM;
  if (j >= 0 && j < KD*NC*DI){
    int k = j / (NC*DI); int r = j % (NC*DI); int c = r / DI, d = r % DI;
    pwT[(k*DI + d)*NC + c] = pw[j];
  }
  int m = i - 384*DM - KD*NC*DI;
  if (m >= 0 && m < DM*DI){ int o = m / DI, d = m % DI; owT[d*DM + o] = ow[m]; }
}

// ---------------- Kernel 1: in_proj -> x_ (L x 192), silu(z) (L x 192) ----------------
__global__ void k_inproj(const float* __restrict__ x, const float* __restrict__ wT,
                         float* __restrict__ xo, float* __restrict__ sz){
  int l0 = blockIdx.x * TL;          // grid = L/TL = 512
  int t  = threadIdx.x;              // 384 threads: one output channel each
  __shared__ float xl[TL][DM];
  for (int j = t; j < TL*DM; j += 384) xl[j / DM][j % DM] = x[l0*DM + j];
  __syncthreads();
  float acc[TL];
  #pragma unroll
  for (int i = 0; i < TL; i++) acc[i] = 0.f;
  #pragma unroll 4
  for (int c = 0; c < DM; c++){
    float wv = wT[c*384 + t];        // coalesced; L1/L2-resident
    #pragma unroll
    for (int i = 0; i < TL; i++) acc[i] += xl[i][c] * wv;  // LDS broadcast
  }
  if (t < DI){
    #pragma unroll
    for (int i = 0; i < TL; i++) xo[(l0 + i)*DI + t] = acc[i];
  } else {
    int z = t - DI;
    #pragma unroll
    for (int i = 0; i < TL; i++) sz[(l0 + i)*DI + z] = silu_f(acc[i]);
  }
}

// ---------------- Kernel 2: depthwise 3x3 conv + bias + silu -> xc ----------------
__global__ void k_conv(const float* __restrict__ xi, const float* __restrict__ cw,
                       const float* __restrict__ cb, float* __restrict__ xc){
  int idx = blockIdx.x * blockDim.x + threadIdx.x;
  if (idx >= L*DI) return;
  int d = idx % DI, l = idx / DI;
  int h = l >> 6, w = l & 63;
  float acc = cb[d];
  #pragma unroll
  for (int dy = 0; dy < 3; dy++){
    int hh = h + dy - 1;
    if (hh < 0 || hh >= HH) continue;
    #pragma unroll
    for (int dx = 0; dx < 3; dx++){
      int ww = w + dx - 1;
      if (ww < 0 || ww >= WW) continue;
      acc += xi[(hh*WW + ww)*DI + d] * cw[(dy*3 + dx)*DI + d];
    }
  }
  xc[idx] = silu_f(acc);
}

// ---------------- Kernel 3: x_dbl[k][l][38] = x_proj_w[k] @ xs[k,:,l] ----------------
__global__ void k_xdbl(const float* __restrict__ xc, const float* __restrict__ pwT,
                       float* __restrict__ xdbl){
  int k    = blockIdx.x >> 9;    // grid = 4*512
  int tile = blockIdx.x & 511;
  int l0   = tile * 8;
  int t    = threadIdx.x;        // 320 threads
  __shared__ float xt[8][DI + 1];   // +1 pad: kills 8-way bank conflict on xt[row][d]
  for (int j = t; j < 8*DI; j += 320){
    int row = j / DI, d = j - row*DI;
    xt[row][d] = xc[spat(k, l0 + row)*DI + d];
  }
  __syncthreads();
  int row = t / 40, c = t % 40;
  if (c < NC){
    const float* pr = pwT + k*DI*NC;
    float acc = 0.f;
    #pragma unroll 8
    for (int d = 0; d < DI; d++) acc += xt[row][d] * pr[d*NC + c];  // pr: lane-consecutive in c
    xdbl[(k*L + l0 + row)*NC + c] = acc;
  }
}

// ---------------- Kernel 4: scan pass 1 — per-chunk aggregates (P, G) ----------------
__global__ void k_scan1(const float* __restrict__ xdbl, const float* __restrict__ xc,
                        const float* __restrict__ dtw, const float* __restrict__ dtb,
                        const float* __restrict__ alogs,
                        float* __restrict__ Pb, float* __restrict__ Gb){
  int k  = blockIdx.x >> 7;   // grid = 4*128
  int ch = blockIdx.x & 127;
  int l0 = ch * CHUNK;
  int d  = threadIdx.x;       // 192 threads
  __shared__ float xd[CHUNK*NC];
  for (int j = d; j < CHUNK*NC; j += DI) xd[j] = xdbl[(k*L + l0)*NC + j];
  float wr[DTR];
  #pragma unroll
  for (int r = 0; r < DTR; r++) wr[r] = dtw[(k*DI + d)*DTR + r];
  float bb = dtb[k*DI + d];
  float A[DSTATE];
  const float4* ap = (const float4*)(alogs + (k*DI + d)*DSTATE);
  #pragma unroll
  for (int q = 0; q < 4; q++){
    float4 v = ap[q];
    A[q*4+0] = -__expf(v.x); A[q*4+1] = -__expf(v.y);
    A[q*4+2] = -__expf(v.z); A[q*4+3] = -__expf(v.w);
  }
  float P[DSTATE], G[DSTATE];
  #pragma unroll
  for (int n = 0; n < DSTATE; n++){ P[n] = 1.f; G[n] = 0.f; }
  __syncthreads();
  for (int i = 0; i < CHUNK; i++){
    int l = l0 + i;
    float xval = xc[spat(k, l)*DI + d];
    const float* row = xd + i*NC;
    float dv = bb;
    #pragma unroll
    for (int r = 0; r < DTR; r++) dv += wr[r] * row[r];
    dv = softplus_f(dv);
    float tv = dv * xval;
    #pragma unroll
    for (int n = 0; n < DSTATE; n++){
      float dA = __expf(dv * A[n]);
      G[n] = dA * G[n] + tv * row[DTR + n];
      P[n] *= dA;
    }
  }
  float* Pp = Pb + ((k*NCHUNK + ch)*DI + d)*DSTATE;
  float* Gp = Gb + ((k*NCHUNK + ch)*DI + d)*DSTATE;
  #pragma unroll
  for (int n = 0; n < DSTATE; n++){ Pp[n] = P[n]; Gp[n] = G[n]; }
}

// ---------------- Kernel 5: scan pass 2 — parallel (Hillis-Steele) prefix over chunks ----
// one block per (k, d); 128 threads = one per chunk; 16 states in registers
__global__ void k_scan2(const float* __restrict__ Pb, const float* __restrict__ Gb,
                        float* __restrict__ Hin){
  int k = blockIdx.x / DI;
  int d = blockIdx.x % DI;
  int c = threadIdx.x;   // chunk id
  float P[DSTATE], G[DSTATE];
  const float* Pp = Pb + ((k*NCHUNK + c)*DI + d)*DSTATE;
  const float* Gp = Gb + ((k*NCHUNK + c)*DI + d)*DSTATE;
  #pragma unroll
  for (int n = 0; n < DSTATE; n++){ P[n] = Pp[n]; G[n] = Gp[n]; }
  __shared__ float sP[NCHUNK][DSTATE + 1];  // +1 pad: conflict-free
  __shared__ float sG[NCHUNK][DSTATE + 1];
  for (int off = 1; off < NCHUNK; off <<= 1){
    #pragma unroll
    for (int n = 0; n < DSTATE; n++){ sP[c][n] = P[n]; sG[c][n] = G[n]; }
    __syncthreads();
    if (c >= off){
      #pragma unroll
      for (int n = 0; n < DSTATE; n++){
        float a1 = sP[c - off][n], b1 = sG[c - off][n];
        G[n] = P[n]*b1 + G[n];     // (a1*a2, a2*b1 + b2)
        P[n] = P[n]*a1;
      }
    }
    __syncthreads();
  }
  #pragma unroll
  for (int n = 0; n < DSTATE; n++) sG[c][n] = G[n];
  __syncthreads();
  float* Hp = Hin + ((k*NCHUNK + c)*DI + d)*DSTATE;
  #pragma unroll
  for (int n = 0; n < DSTATE; n++) Hp[n] = (c == 0) ? 0.f : sG[c - 1][n];
}

// ---------------- Kernel 6: scan pass 3 — replay chunks, emit out_y ----------------
__global__ void k_scan3(const float* __restrict__ xdbl, const float* __restrict__ xc,
                        const float* __restrict__ dtw, const float* __restrict__ dtb,
                        const float* __restrict__ alogs, const float* __restrict__ Dsv,
                        const float* __restrict__ Hin, float* __restrict__ outy){
  int k  = blockIdx.x >> 7;
  int ch = blockIdx.x & 127;
  int l0 = ch * CHUNK;
  int d  = threadIdx.x;
  __shared__ float xd[CHUNK*NC];
  for (int j = d; j < CHUNK*NC; j += DI) xd[j] = xdbl[(k*L + l0)*NC + j];
  float wr[DTR];
  #pragma unroll
  for (int r = 0; r < DTR; r++) wr[r] = dtw[(k*DI + d)*DTR + r];
  float bb = dtb[k*DI + d];
  float A[DSTATE];
  const float4* ap = (const float4*)(alogs + (k*DI + d)*DSTATE);
  #pragma unroll
  for (int q = 0; q < 4; q++){
    float4 v = ap[q];
    A[q*4+0] = -__expf(v.x); A[q*4+1] = -__expf(v.y);
    A[q*4+2] = -__expf(v.z); A[q*4+3] = -__expf(v.w);
  }
  float h[DSTATE];
  #pragma unroll
  for (int n = 0; n < DSTATE; n++) h[n] = Hin[((k*NCHUNK + ch)*DI + d)*DSTATE + n];
  float Dv = Dsv[k*DI + d];
  __syncthreads();
  for (int i = 0; i < CHUNK; i++){
    int l = l0 + i;
    float xval = xc[spat(k, l)*DI + d];
    const float* row = xd + i*NC;
    float dv = bb;
    #pragma unroll
    for (int r = 0; r < DTR; r++) dv += wr[r] * row[r];
    dv = softplus_f(dv);
    float tv = dv * xval;
    float y = Dv * xval;
    #pragma unroll
    for (int n = 0; n < DSTATE; n++){
      float dA = __expf(dv * A[n]);
      h[n] = dA * h[n] + tv * row[DTR + n];
      y += h[n] * row[DTR + DSTATE + n];
    }
    outy[(k*L + l)*DI + d] = y;
  }
}

// ---------------- Kernel 7: sum over k + LayerNorm + *silu(z) + out proj ----------------
__global__ void k_final(const float* __restrict__ outy, const float* __restrict__ sz,
                        const float* __restrict__ g, const float* __restrict__ b,
                        const float* __restrict__ owT, float* __restrict__ out){
  int l = blockIdx.x, t = threadIdx.x;  // 192 threads
  __shared__ float ym[DI];
  __shared__ float part[DI];
  __shared__ float red[6];
  float y = 0.f;
  #pragma unroll
  for (int k = 0; k < KD; k++) y += outy[(k*L + l)*DI + t];
  float s = y, s2 = y*y;
  #pragma unroll
  for (int off = 32; off; off >>= 1){ s += __shfl_down(s, off); s2 += __shfl_down(s2, off); }
  int wave = t >> 6, lane = t & 63;
  if (lane == 0){ red[wave] = s; red[3 + wave] = s2; }
  __syncthreads();
  float S  = red[0] + red[1] + red[2];
  float SQ = red[3] + red[4] + red[5];
  float mu  = S * (1.f/DI);
  float var = SQ * (1.f/DI) - mu*mu;
  float yn = (y - mu) * rsqrtf(var + 1e-5f) * g[t] + b[t];
  ym[t] = yn * sz[l*DI + t];
  __syncthreads();
  // out-proj: thread t -> output o = t%96, over half of d; combine halves via LDS
  int o  = (t < DM) ? t : (t - DM);
  int d0 = (t < DM) ? 0 : DM;
  float acc = 0.f;
  #pragma unroll 8
  for (int dd = 0; dd < DM; dd++){
    int d = d0 + dd;
    acc += ym[d] * owT[d*DM + o];   // owT: lane-consecutive in o; ym: broadcast
  }
  part[t] = acc;
  __syncthreads();
  if (t < DM) out[l*DM + t] = part[t] + part[DM + t];
}

extern "C" void kernel_launch(void* const* d_in, const int* in_sizes, int n_in,
                              void* d_out, int out_size, void* d_ws, size_t ws_size,
                              hipStream_t stream){
  const float* x   = (const float*)d_in[0];
  const float* ipw = (const float*)d_in[1];
  const float* cw  = (const float*)d_in[2];
  const float* cb  = (const float*)d_in[3];
  const float* pw  = (const float*)d_in[4];
  const float* dtw = (const float*)d_in[5];
  const float* dtb = (const float*)d_in[6];
  const float* alg = (const float*)d_in[7];
  const float* Dsv = (const float*)d_in[8];
  const float* lng = (const float*)d_in[9];
  const float* lnb = (const float*)d_in[10];
  const float* ow  = (const float*)d_in[11];
  float* out = (float*)d_out;

  float* ws    = (float*)d_ws;
  float* x_    = ws; ws += L*DI;
  float* sz    = ws; ws += L*DI;
  float* xc    = ws; ws += L*DI;
  float* xdbl  = ws; ws += KD*L*NC;
  float* Pb    = ws; ws += KD*NCHUNK*DI*DSTATE;
  float* Gb    = ws; ws += KD*NCHUNK*DI*DSTATE;
  float* Hin   = ws; ws += KD*NCHUNK*DI*DSTATE;
  float* oy    = ws; ws += KD*L*DI;
  float* ipwT  = ws; ws += 384*DM;
  float* pwT   = ws; ws += KD*NC*DI;
  float* owT   = ws; ws += DM*DI;

  k_prep<<<(384*DM + KD*NC*DI + DM*DI + 255)/256, 256, 0, stream>>>(ipw, pw, ow, ipwT, pwT, owT);
  k_inproj<<<L/TL, 384, 0, stream>>>(x, ipwT, x_, sz);
  k_conv<<<(L*DI + 255)/256, 256, 0, stream>>>(x_, cw, cb, xc);
  k_xdbl<<<KD*512, 320, 0, stream>>>(xc, pwT, xdbl);
  k_scan1<<<KD*NCHUNK, DI, 0, stream>>>(xdbl, xc, dtw, dtb, alg, Pb, Gb);
  k_scan2<<<KD*DI, NCHUNK, 0, stream>>>(Pb, Gb, Hin);
  k_scan3<<<KD*NCHUNK, DI, 0, stream>>>(xdbl, xc, dtw, dtb, alg, Dsv, Hin, oy);
  k_final<<<L, DI, 0, stream>>>(oy, sz, lng, lnb, owT, out);
}